// Round 3
// baseline (3955.204 us; speedup 1.0000x reference)
//
#include <hip/hip_runtime.h>
#include <hip/hip_bf16.h>

// Problem dims
constexpr int NV   = 10000;  // vocab
constexpr int NE   = 512;    // embed
constexpr int NENC = 2048;   // encoder dim
constexpr int ND   = 512;    // decoder dim
constexpr int NA   = 512;    // attention dim
constexpr int NB   = 64;     // batch
constexpr int NL   = 49;     // locations
constexpr int NT   = 20;     // steps
constexpr int KX   = NE + NENC + ND;  // 3072 : x = [emb | context | h]

// ---------------------------------------------------------------------------
// K0: h0 = mean_l(enc) @ W_init_h + b ; c0 likewise.  One block per batch row.
// ---------------------------------------------------------------------------
__launch_bounds__(256)
__global__ void k_init(const float* __restrict__ enc,   // (B,L,ENC) f32
                       const float* __restrict__ Wh,    // (ENC,D)
                       const float* __restrict__ bh,    // (D)
                       const float* __restrict__ Wc,    // (ENC,D)
                       const float* __restrict__ bc,    // (D)
                       float* __restrict__ h, float* __restrict__ c)
{
    __shared__ float mean[NENC];
    const int b = blockIdx.x, tid = threadIdx.x;
    for (int e = tid; e < NENC; e += 256) {
        const float* p = enc + (size_t)b * NL * NENC + e;
        float s = 0.f;
        #pragma unroll 7
        for (int l = 0; l < NL; ++l) s += p[(size_t)l * NENC];
        mean[e] = s * (1.0f / NL);
    }
    __syncthreads();
    for (int d = tid; d < ND; d += 256) {
        float hs = bh[d], cs = bc[d];
        for (int e = 0; e < NENC; ++e) {
            float m = mean[e];
            hs = fmaf(m, Wh[(size_t)e * ND + d], hs);
            cs = fmaf(m, Wc[(size_t)e * ND + d], cs);
        }
        h[b * ND + d] = hs;
        c[b * ND + d] = cs;
    }
}

// ---------------------------------------------------------------------------
// K1: enc_proj (B*L,A) = enc (B*L,ENC) @ W_enc_att (ENC,A) + b_enc_att
// Tiled GEMM, BM=BN=64, BK=16, 256 threads, 4x4 per thread.
// ---------------------------------------------------------------------------
__launch_bounds__(256)
__global__ void k_encproj(const float* __restrict__ Am,  // (3136,2048) f32
                          const float* __restrict__ Bm,  // (2048,512)  f32
                          const float* __restrict__ bias,// (512)
                          float* __restrict__ Cm)        // (3136,512) f32
{
    constexpr int BM = 64, BN = 64, BK = 16;
    __shared__ float As[BK][BM + 1];
    __shared__ float Bs[BK][BN + 1];
    const int tid = threadIdx.x;
    const int gm = blockIdx.x * BM;
    const int gn = blockIdx.y * BN;
    const int arow = tid >> 2, ak = (tid & 3) * 4;
    const int bkr = tid >> 4, bn = (tid & 15) * 4;
    const int ty = tid >> 4, tx = tid & 15;
    float acc[4][4] = {};
    for (int kb = 0; kb < NENC; kb += BK) {
        float4 av = *(const float4*)(Am + (size_t)(gm + arow) * NENC + kb + ak);
        As[ak + 0][arow] = av.x;
        As[ak + 1][arow] = av.y;
        As[ak + 2][arow] = av.z;
        As[ak + 3][arow] = av.w;
        float4 bv = *(const float4*)(Bm + (size_t)(kb + bkr) * NA + gn + bn);
        Bs[bkr][bn + 0] = bv.x;
        Bs[bkr][bn + 1] = bv.y;
        Bs[bkr][bn + 2] = bv.z;
        Bs[bkr][bn + 3] = bv.w;
        __syncthreads();
        #pragma unroll
        for (int kk = 0; kk < BK; ++kk) {
            float a[4], bb[4];
            #pragma unroll
            for (int i = 0; i < 4; ++i) a[i] = As[kk][ty * 4 + i];
            #pragma unroll
            for (int j = 0; j < 4; ++j) bb[j] = Bs[kk][tx * 4 + j];
            #pragma unroll
            for (int i = 0; i < 4; ++i)
                #pragma unroll
                for (int j = 0; j < 4; ++j)
                    acc[i][j] = fmaf(a[i], bb[j], acc[i][j]);
        }
        __syncthreads();
    }
    #pragma unroll
    for (int i = 0; i < 4; ++i)
        #pragma unroll
        for (int j = 0; j < 4; ++j) {
            int n = gn + tx * 4 + j;
            Cm[(size_t)(gm + ty * 4 + i) * NA + n] = acc[i][j] + bias[n];
        }
}

// ---------------------------------------------------------------------------
// K_att: per step t, one block per batch row b:
//   dec_proj = h@W_dec_att+b ; scores = relu(enc_proj+dec_proj)@w_full+b ;
//   alpha = softmax(scores) -> d_out ; context = alpha@enc ;
//   x[b] = [emb_table[cap[b,t]] | context | h]
// ---------------------------------------------------------------------------
__launch_bounds__(256)
__global__ void k_att(int t,
                      const float* __restrict__ h,
                      const float* __restrict__ enc_proj,      // (B,L,A) f32
                      const float* __restrict__ enc,           // (B,L,ENC) f32
                      const float* __restrict__ Wda,           // (D,A)
                      const float* __restrict__ bda,           // (A)
                      const float* __restrict__ wf,            // (A)
                      const float* __restrict__ bfs,           // scalar
                      const float* __restrict__ embt,          // (V,E)
                      const int* __restrict__ captions,        // (B,T)
                      float* __restrict__ x,                   // (B,KX) f32
                      float* __restrict__ alpha_out)           // (B,T,L) f32
{
    __shared__ float hb[ND];
    __shared__ float dp[NA];
    __shared__ float al[64];
    const int b = blockIdx.x, tid = threadIdx.x;

    for (int d = tid; d < ND; d += 256) {
        float v = h[b * ND + d];
        hb[d] = v;
        x[(size_t)b * KX + NE + NENC + d] = v;   // h tail of x (for W_hh)
    }
    const int tok = captions[b * NT + t];
    for (int j = tid; j < NE; j += 256)
        x[(size_t)b * KX + j] = embt[(size_t)tok * NE + j];
    __syncthreads();

    // dec_proj
    for (int a = tid; a < NA; a += 256) {
        float s = bda[a];
        #pragma unroll 8
        for (int d = 0; d < ND; ++d) s = fmaf(hb[d], Wda[(size_t)d * NA + a], s);
        dp[a] = s;
    }
    __syncthreads();

    // scores (one wave per l, strided)
    const int wave = tid >> 6, lane = tid & 63;
    const float bfull = bfs[0];
    for (int l = wave; l < NL; l += 4) {
        const float* ep = enc_proj + ((size_t)b * NL + l) * NA;
        float s = 0.f;
        #pragma unroll
        for (int a = lane; a < NA; a += 64) {
            float v = ep[a] + dp[a];
            v = v > 0.f ? v : 0.f;
            s = fmaf(v, wf[a], s);
        }
        #pragma unroll
        for (int off = 32; off > 0; off >>= 1) s += __shfl_down(s, off, 64);
        if (lane == 0) al[l] = s + bfull;
    }
    __syncthreads();

    // softmax over L=49 (first wave only)
    if (tid < 64) {
        float v = (tid < NL) ? al[tid] : -1e30f;
        float m = v;
        #pragma unroll
        for (int off = 32; off > 0; off >>= 1) m = fmaxf(m, __shfl_xor(m, off, 64));
        float e = (tid < NL) ? expf(v - m) : 0.f;
        float s = e;
        #pragma unroll
        for (int off = 32; off > 0; off >>= 1) s += __shfl_xor(s, off, 64);
        float a = e / s;
        if (tid < NL) {
            al[tid] = a;
            alpha_out[((size_t)b * NT + t) * NL + tid] = a;
        }
    }
    __syncthreads();

    // context -> x middle section
    for (int e = tid; e < NENC; e += 256) {
        const float* p = enc + (size_t)b * NL * NENC + e;
        float s = 0.f;
        #pragma unroll 7
        for (int l = 0; l < NL; ++l) s = fmaf(al[l], p[(size_t)l * NENC], s);
        x[(size_t)b * KX + NE + e] = s;
    }
}

// ---------------------------------------------------------------------------
// K_gates: gates partials (SK,B,2048) = x(B,3072) @ [W_ih|W_hh]^T, split-K=4.
// BM=64 (all B), BN=32, BK=16, 256 threads, 4x2 per thread.
// ---------------------------------------------------------------------------
__launch_bounds__(256)
__global__ void k_gates(const float* __restrict__ x,    // (B,KX)
                        const float* __restrict__ Wih,  // (2048, 2560)
                        const float* __restrict__ Whh,  // (2048, 512)
                        float* __restrict__ gpart)      // (4,B,2048)
{
    constexpr int BN = 32, BK = 16, KC = KX / 4;  // 768 per split
    __shared__ float As[BK][NB + 1];
    __shared__ float Bs[BK][BN + 1];
    const int tid = threadIdx.x;
    const int gn = blockIdx.x * BN;
    const int z  = blockIdx.y;
    const int arow = tid >> 2, ak = (tid & 3) * 4;
    const int brow = tid >> 3, bk2 = (tid & 7) * 2;
    const int ty = tid >> 4, tx = tid & 15;
    float acc[4][2] = {};
    for (int kb = z * KC; kb < (z + 1) * KC; kb += BK) {
        float4 av = *(const float4*)(x + (size_t)arow * KX + kb + ak);
        As[ak + 0][arow] = av.x;
        As[ak + 1][arow] = av.y;
        As[ak + 2][arow] = av.z;
        As[ak + 3][arow] = av.w;
        const float* src;
        if (kb < NE + NENC)
            src = Wih + (size_t)(gn + brow) * (NE + NENC) + kb + bk2;
        else
            src = Whh + (size_t)(gn + brow) * ND + (kb - (NE + NENC)) + bk2;
        float2 bv = *(const float2*)src;
        Bs[bk2 + 0][brow] = bv.x;
        Bs[bk2 + 1][brow] = bv.y;
        __syncthreads();
        #pragma unroll
        for (int kk = 0; kk < BK; ++kk) {
            float a[4], bb[2];
            #pragma unroll
            for (int i = 0; i < 4; ++i) a[i] = As[kk][ty * 4 + i];
            bb[0] = Bs[kk][tx * 2 + 0];
            bb[1] = Bs[kk][tx * 2 + 1];
            #pragma unroll
            for (int i = 0; i < 4; ++i) {
                acc[i][0] = fmaf(a[i], bb[0], acc[i][0]);
                acc[i][1] = fmaf(a[i], bb[1], acc[i][1]);
            }
        }
        __syncthreads();
    }
    float* outp = gpart + (size_t)z * NB * (4 * ND);
    #pragma unroll
    for (int i = 0; i < 4; ++i)
        #pragma unroll
        for (int j = 0; j < 2; ++j)
            outp[(size_t)(ty * 4 + i) * (4 * ND) + gn + tx * 2 + j] = acc[i][j];
}

// ---------------------------------------------------------------------------
// K_lstm: sum split-K partials + biases -> i,f,g,o -> update h,c in place.
// ---------------------------------------------------------------------------
__launch_bounds__(256)
__global__ void k_lstm(const float* __restrict__ gpart,  // (4,B,2048)
                       const float* __restrict__ bih,    // (2048)
                       const float* __restrict__ bhh,    // (2048)
                       float* __restrict__ h, float* __restrict__ c)
{
    const int idx = blockIdx.x * 256 + threadIdx.x;  // 0..32767
    const int b = idx >> 9, d = idx & 511;
    constexpr int G = 4 * ND;
    float gi = bih[d]        + bhh[d];
    float gf = bih[d + 512]  + bhh[d + 512];
    float gg = bih[d + 1024] + bhh[d + 1024];
    float go = bih[d + 1536] + bhh[d + 1536];
    #pragma unroll
    for (int z = 0; z < 4; ++z) {
        const float* gp = gpart + ((size_t)z * NB + b) * G;
        gi += gp[d];
        gf += gp[d + 512];
        gg += gp[d + 1024];
        go += gp[d + 1536];
    }
    float i = 1.f / (1.f + expf(-gi));
    float f = 1.f / (1.f + expf(-gf));
    float g = tanhf(gg);
    float o = 1.f / (1.f + expf(-go));
    float cn = f * c[idx] + i * g;
    float hn = o * tanhf(cn);
    c[idx] = cn;
    h[idx] = hn;
}

// ---------------------------------------------------------------------------
// K_logits: (B,V) = h(B,512) @ W_out(512,V) + b_out -> f32 d_out[:, t, :]
// BM=64 (all B), BN=64, BK=16, 4x4 per thread, N-edge guarded (V=10000).
// ---------------------------------------------------------------------------
__launch_bounds__(256)
__global__ void k_logits(int t, const float* __restrict__ h,
                         const float* __restrict__ Wout, // (512, V)
                         const float* __restrict__ bout, // (V)
                         float* __restrict__ out)        // (B,T,V) f32
{
    constexpr int BN = 64, BK = 16;
    __shared__ float As[BK][NB + 1];
    __shared__ float Bs[BK][BN + 1];
    const int tid = threadIdx.x;
    const int gn = blockIdx.x * BN;
    const int arow = tid >> 2, ak = (tid & 3) * 4;
    const int bkr = tid >> 4, bn = (tid & 15) * 4;
    const int ty = tid >> 4, tx = tid & 15;
    float acc[4][4] = {};
    const bool full = (gn + BN <= NV);
    for (int kb = 0; kb < ND; kb += BK) {
        float4 av = *(const float4*)(h + (size_t)arow * ND + kb + ak);
        As[ak + 0][arow] = av.x;
        As[ak + 1][arow] = av.y;
        As[ak + 2][arow] = av.z;
        As[ak + 3][arow] = av.w;
        const float* src = Wout + (size_t)(kb + bkr) * NV + gn + bn;
        if (full) {
            float4 bv = *(const float4*)src;
            Bs[bkr][bn + 0] = bv.x;
            Bs[bkr][bn + 1] = bv.y;
            Bs[bkr][bn + 2] = bv.z;
            Bs[bkr][bn + 3] = bv.w;
        } else {
            #pragma unroll
            for (int i = 0; i < 4; ++i)
                Bs[bkr][bn + i] = (gn + bn + i < NV) ? src[i] : 0.f;
        }
        __syncthreads();
        #pragma unroll
        for (int kk = 0; kk < BK; ++kk) {
            float a[4], bb[4];
            #pragma unroll
            for (int i = 0; i < 4; ++i) a[i] = As[kk][ty * 4 + i];
            #pragma unroll
            for (int j = 0; j < 4; ++j) bb[j] = Bs[kk][tx * 4 + j];
            #pragma unroll
            for (int i = 0; i < 4; ++i)
                #pragma unroll
                for (int j = 0; j < 4; ++j)
                    acc[i][j] = fmaf(a[i], bb[j], acc[i][j]);
        }
        __syncthreads();
    }
    #pragma unroll
    for (int i = 0; i < 4; ++i) {
        const int b = ty * 4 + i;
        #pragma unroll
        for (int j = 0; j < 4; ++j) {
            const int v = gn + tx * 4 + j;
            if (v < NV)
                out[((size_t)b * NT + t) * NV + v] = acc[i][j] + bout[v];
        }
    }
}

// ---------------------------------------------------------------------------
extern "C" void kernel_launch(void* const* d_in, const int* in_sizes, int n_in,
                              void* d_out, int out_size, void* d_ws, size_t ws_size,
                              hipStream_t stream) {
    const float* enc  = (const float*)d_in[0];
    const int*   caps = (const int*)d_in[1];
    const float* embt = (const float*)d_in[2];
    const float* Wea  = (const float*)d_in[3];
    const float* bea  = (const float*)d_in[4];
    const float* Wda  = (const float*)d_in[5];
    const float* bda  = (const float*)d_in[6];
    const float* wf   = (const float*)d_in[7];
    const float* bfs  = (const float*)d_in[8];
    const float* Wih  = (const float*)d_in[9];
    const float* bih  = (const float*)d_in[10];
    const float* Whh  = (const float*)d_in[11];
    const float* bhh  = (const float*)d_in[12];
    const float* Wh0  = (const float*)d_in[13];
    const float* bh0  = (const float*)d_in[14];
    const float* Wc0  = (const float*)d_in[15];
    const float* bc0  = (const float*)d_in[16];
    const float* Wout = (const float*)d_in[17];
    const float* bout = (const float*)d_in[18];

    float* out = (float*)d_out;                       // logits (B,T,V) f32
    float* alpha_out = out + (size_t)NB * NT * NV;    // alphas (B,T,L) f32

    float* ws = (float*)d_ws;
    float* enc_proj = ws;                                   // 64*49*512
    float* h        = enc_proj + (size_t)NB * NL * NA;      // 64*512
    float* c        = h + NB * ND;                          // 64*512
    float* x        = c + NB * ND;                          // 64*3072
    float* gpart    = x + (size_t)NB * KX;                  // 4*64*2048

    hipLaunchKernelGGL(k_init, dim3(NB), dim3(256), 0, stream,
                       enc, Wh0, bh0, Wc0, bc0, h, c);
    hipLaunchKernelGGL(k_encproj, dim3(NB * NL / 64, NA / 64), dim3(256), 0, stream,
                       enc, Wea, bea, enc_proj);

    for (int t = 0; t < NT; ++t) {
        hipLaunchKernelGGL(k_att, dim3(NB), dim3(256), 0, stream,
                           t, h, enc_proj, enc, Wda, bda, wf, bfs, embt, caps, x, alpha_out);
        hipLaunchKernelGGL(k_gates, dim3((4 * ND) / 32, 4), dim3(256), 0, stream,
                           x, Wih, Whh, gpart);
        hipLaunchKernelGGL(k_lstm, dim3(NB * ND / 256), dim3(256), 0, stream,
                           gpart, bih, bhh, h, c);
        hipLaunchKernelGGL(k_logits, dim3((NV + 63) / 64), dim3(256), 0, stream,
                           t, h, Wout, bout, out);
    }
}

// Round 4
// 3627.042 us; speedup vs baseline: 1.0905x; 1.0905x over previous
//
#include <hip/hip_runtime.h>
#include <hip/hip_bf16.h>

// Problem dims
constexpr int NV   = 10000;  // vocab
constexpr int NE   = 512;    // embed
constexpr int NENC = 2048;   // encoder dim
constexpr int ND   = 512;    // decoder dim
constexpr int NA   = 512;    // attention dim
constexpr int NB   = 64;     // batch
constexpr int NL   = 49;     // locations
constexpr int NT   = 20;     // steps
constexpr int KX   = NE + NENC + ND;  // 3072 : x = [emb | context | h]

// ---------------------------------------------------------------------------
// K_mean: mean over L. grid (B, NENC/256), 256 threads. Coalesced.
// ---------------------------------------------------------------------------
__launch_bounds__(256)
__global__ void k_mean(const float* __restrict__ enc,   // (B,L,ENC)
                       float* __restrict__ mean)        // (B,ENC)
{
    const int b = blockIdx.x;
    const int e = blockIdx.y * 256 + threadIdx.x;
    const float* p = enc + (size_t)b * NL * NENC + e;
    float s = 0.f;
    #pragma unroll 7
    for (int l = 0; l < NL; ++l) s += p[(size_t)l * NENC];
    mean[(size_t)b * NENC + e] = s * (1.0f / NL);
}

// ---------------------------------------------------------------------------
// K_init_gemm: [h|c](64,1024) = mean(64,2048) @ [W_init_h|W_init_c] + bias.
// BM=64 (all B), BN=64, BK=16, 256 threads, 4x4/thread. grid.x = 16.
// ---------------------------------------------------------------------------
__launch_bounds__(256)
__global__ void k_init_gemm(const float* __restrict__ mean, // (B,ENC)
                            const float* __restrict__ Wh,   // (ENC,D)
                            const float* __restrict__ bh,
                            const float* __restrict__ Wc,   // (ENC,D)
                            const float* __restrict__ bc,
                            float* __restrict__ h, float* __restrict__ c)
{
    constexpr int BN = 64, BK = 16;
    __shared__ float As[BK][NB + 1];
    __shared__ float Bs[BK][BN + 1];
    const int tid = threadIdx.x;
    const bool isC = blockIdx.x >= (ND / BN);
    const float* W    = isC ? Wc : Wh;
    const float* bias = isC ? bc : bh;
    float* dst        = isC ? c  : h;
    const int gn = (blockIdx.x - (isC ? ND / BN : 0)) * BN;
    const int arow = tid >> 2, ak = (tid & 3) * 4;
    const int bkr = tid >> 4, bn = (tid & 15) * 4;
    const int ty = tid >> 4, tx = tid & 15;
    float acc[4][4] = {};
    for (int kb = 0; kb < NENC; kb += BK) {
        float4 av = *(const float4*)(mean + (size_t)arow * NENC + kb + ak);
        As[ak + 0][arow] = av.x;
        As[ak + 1][arow] = av.y;
        As[ak + 2][arow] = av.z;
        As[ak + 3][arow] = av.w;
        float4 bv = *(const float4*)(W + (size_t)(kb + bkr) * ND + gn + bn);
        Bs[bkr][bn + 0] = bv.x;
        Bs[bkr][bn + 1] = bv.y;
        Bs[bkr][bn + 2] = bv.z;
        Bs[bkr][bn + 3] = bv.w;
        __syncthreads();
        #pragma unroll
        for (int kk = 0; kk < BK; ++kk) {
            float a[4], bb[4];
            #pragma unroll
            for (int i = 0; i < 4; ++i) a[i] = As[kk][ty * 4 + i];
            #pragma unroll
            for (int j = 0; j < 4; ++j) bb[j] = Bs[kk][tx * 4 + j];
            #pragma unroll
            for (int i = 0; i < 4; ++i)
                #pragma unroll
                for (int j = 0; j < 4; ++j)
                    acc[i][j] = fmaf(a[i], bb[j], acc[i][j]);
        }
        __syncthreads();
    }
    #pragma unroll
    for (int i = 0; i < 4; ++i)
        #pragma unroll
        for (int j = 0; j < 4; ++j) {
            int n = gn + tx * 4 + j;
            dst[(size_t)(ty * 4 + i) * ND + n] = acc[i][j] + bias[n];
        }
}

// ---------------------------------------------------------------------------
// K1: enc_proj (B*L,A) = enc (B*L,ENC) @ W_enc_att (ENC,A) + b_enc_att
// Tiled GEMM, BM=BN=64, BK=16, 256 threads, 4x4 per thread.
// ---------------------------------------------------------------------------
__launch_bounds__(256)
__global__ void k_encproj(const float* __restrict__ Am,  // (3136,2048) f32
                          const float* __restrict__ Bm,  // (2048,512)  f32
                          const float* __restrict__ bias,// (512)
                          float* __restrict__ Cm)        // (3136,512) f32
{
    constexpr int BM = 64, BN = 64, BK = 16;
    __shared__ float As[BK][BM + 1];
    __shared__ float Bs[BK][BN + 1];
    const int tid = threadIdx.x;
    const int gm = blockIdx.x * BM;
    const int gn = blockIdx.y * BN;
    const int arow = tid >> 2, ak = (tid & 3) * 4;
    const int bkr = tid >> 4, bn = (tid & 15) * 4;
    const int ty = tid >> 4, tx = tid & 15;
    float acc[4][4] = {};
    for (int kb = 0; kb < NENC; kb += BK) {
        float4 av = *(const float4*)(Am + (size_t)(gm + arow) * NENC + kb + ak);
        As[ak + 0][arow] = av.x;
        As[ak + 1][arow] = av.y;
        As[ak + 2][arow] = av.z;
        As[ak + 3][arow] = av.w;
        float4 bv = *(const float4*)(Bm + (size_t)(kb + bkr) * NA + gn + bn);
        Bs[bkr][bn + 0] = bv.x;
        Bs[bkr][bn + 1] = bv.y;
        Bs[bkr][bn + 2] = bv.z;
        Bs[bkr][bn + 3] = bv.w;
        __syncthreads();
        #pragma unroll
        for (int kk = 0; kk < BK; ++kk) {
            float a[4], bb[4];
            #pragma unroll
            for (int i = 0; i < 4; ++i) a[i] = As[kk][ty * 4 + i];
            #pragma unroll
            for (int j = 0; j < 4; ++j) bb[j] = Bs[kk][tx * 4 + j];
            #pragma unroll
            for (int i = 0; i < 4; ++i)
                #pragma unroll
                for (int j = 0; j < 4; ++j)
                    acc[i][j] = fmaf(a[i], bb[j], acc[i][j]);
        }
        __syncthreads();
    }
    #pragma unroll
    for (int i = 0; i < 4; ++i)
        #pragma unroll
        for (int j = 0; j < 4; ++j) {
            int n = gn + tx * 4 + j;
            Cm[(size_t)(gm + ty * 4 + i) * NA + n] = acc[i][j] + bias[n];
        }
}

// ---------------------------------------------------------------------------
// K_decproj: dp(64,512) = h(64,512) @ Wda(512,512) + bda. grid 8, BN=64.
// ---------------------------------------------------------------------------
__launch_bounds__(256)
__global__ void k_decproj(const float* __restrict__ h,
                          const float* __restrict__ Wda,  // (D,A)
                          const float* __restrict__ bda,
                          float* __restrict__ dp)         // (B,A)
{
    constexpr int BN = 64, BK = 16;
    __shared__ float As[BK][NB + 1];
    __shared__ float Bs[BK][BN + 1];
    const int tid = threadIdx.x;
    const int gn = blockIdx.x * BN;
    const int arow = tid >> 2, ak = (tid & 3) * 4;
    const int bkr = tid >> 4, bn = (tid & 15) * 4;
    const int ty = tid >> 4, tx = tid & 15;
    float acc[4][4] = {};
    for (int kb = 0; kb < ND; kb += BK) {
        float4 av = *(const float4*)(h + (size_t)arow * ND + kb + ak);
        As[ak + 0][arow] = av.x;
        As[ak + 1][arow] = av.y;
        As[ak + 2][arow] = av.z;
        As[ak + 3][arow] = av.w;
        float4 bv = *(const float4*)(Wda + (size_t)(kb + bkr) * NA + gn + bn);
        Bs[bkr][bn + 0] = bv.x;
        Bs[bkr][bn + 1] = bv.y;
        Bs[bkr][bn + 2] = bv.z;
        Bs[bkr][bn + 3] = bv.w;
        __syncthreads();
        #pragma unroll
        for (int kk = 0; kk < BK; ++kk) {
            float a[4], bb[4];
            #pragma unroll
            for (int i = 0; i < 4; ++i) a[i] = As[kk][ty * 4 + i];
            #pragma unroll
            for (int j = 0; j < 4; ++j) bb[j] = Bs[kk][tx * 4 + j];
            #pragma unroll
            for (int i = 0; i < 4; ++i)
                #pragma unroll
                for (int j = 0; j < 4; ++j)
                    acc[i][j] = fmaf(a[i], bb[j], acc[i][j]);
        }
        __syncthreads();
    }
    #pragma unroll
    for (int i = 0; i < 4; ++i)
        #pragma unroll
        for (int j = 0; j < 4; ++j) {
            int n = gn + tx * 4 + j;
            dp[(size_t)(ty * 4 + i) * NA + n] = acc[i][j] + bda[n];
        }
}

// ---------------------------------------------------------------------------
// K_att: per step t, one block per batch row b. dec_proj precomputed (dpg).
//   scores = relu(enc_proj+dp)@w_full+b ; alpha = softmax -> d_out ;
//   context = alpha@enc ; x[b] = [emb_table[cap[b,t]] | context | h]
// ---------------------------------------------------------------------------
__launch_bounds__(256)
__global__ void k_att(int t,
                      const float* __restrict__ h,
                      const float* __restrict__ dpg,           // (B,A) f32
                      const float* __restrict__ enc_proj,      // (B,L,A) f32
                      const float* __restrict__ enc,           // (B,L,ENC) f32
                      const float* __restrict__ wf,            // (A)
                      const float* __restrict__ bfs,           // scalar
                      const float* __restrict__ embt,          // (V,E)
                      const int* __restrict__ captions,        // (B,T)
                      float* __restrict__ x,                   // (B,KX) f32
                      float* __restrict__ alpha_out)           // (B,T,L) f32
{
    __shared__ float dp[NA];
    __shared__ float al[64];
    const int b = blockIdx.x, tid = threadIdx.x;

    for (int d = tid; d < ND; d += 256)
        x[(size_t)b * KX + NE + NENC + d] = h[b * ND + d];   // h tail of x
    for (int a = tid; a < NA; a += 256)
        dp[a] = dpg[(size_t)b * NA + a];
    const int tok = captions[b * NT + t];
    for (int j = tid; j < NE; j += 256)
        x[(size_t)b * KX + j] = embt[(size_t)tok * NE + j];
    __syncthreads();

    // scores (one wave per l, strided)
    const int wave = tid >> 6, lane = tid & 63;
    const float bfull = bfs[0];
    for (int l = wave; l < NL; l += 4) {
        const float* ep = enc_proj + ((size_t)b * NL + l) * NA;
        float s = 0.f;
        #pragma unroll
        for (int a = lane; a < NA; a += 64) {
            float v = ep[a] + dp[a];
            v = v > 0.f ? v : 0.f;
            s = fmaf(v, wf[a], s);
        }
        #pragma unroll
        for (int off = 32; off > 0; off >>= 1) s += __shfl_down(s, off, 64);
        if (lane == 0) al[l] = s + bfull;
    }
    __syncthreads();

    // softmax over L=49 (first wave only)
    if (tid < 64) {
        float v = (tid < NL) ? al[tid] : -1e30f;
        float m = v;
        #pragma unroll
        for (int off = 32; off > 0; off >>= 1) m = fmaxf(m, __shfl_xor(m, off, 64));
        float e = (tid < NL) ? expf(v - m) : 0.f;
        float s = e;
        #pragma unroll
        for (int off = 32; off > 0; off >>= 1) s += __shfl_xor(s, off, 64);
        float a = e / s;
        if (tid < NL) {
            al[tid] = a;
            alpha_out[((size_t)b * NT + t) * NL + tid] = a;
        }
    }
    __syncthreads();

    // context -> x middle section
    for (int e = tid; e < NENC; e += 256) {
        const float* p = enc + (size_t)b * NL * NENC + e;
        float s = 0.f;
        #pragma unroll 7
        for (int l = 0; l < NL; ++l) s = fmaf(al[l], p[(size_t)l * NENC], s);
        x[(size_t)b * KX + NE + e] = s;
    }
}

// ---------------------------------------------------------------------------
// K_gates: gates partials (SK,B,2048) = x(B,3072) @ [W_ih|W_hh]^T, split-K=4.
// BM=64 (all B), BN=32, BK=16, 256 threads, 4x2 per thread.
// ---------------------------------------------------------------------------
__launch_bounds__(256)
__global__ void k_gates(const float* __restrict__ x,    // (B,KX)
                        const float* __restrict__ Wih,  // (2048, 2560)
                        const float* __restrict__ Whh,  // (2048, 512)
                        float* __restrict__ gpart)      // (4,B,2048)
{
    constexpr int BN = 32, BK = 16, KC = KX / 4;  // 768 per split
    __shared__ float As[BK][NB + 1];
    __shared__ float Bs[BK][BN + 1];
    const int tid = threadIdx.x;
    const int gn = blockIdx.x * BN;
    const int z  = blockIdx.y;
    const int arow = tid >> 2, ak = (tid & 3) * 4;
    const int brow = tid >> 3, bk2 = (tid & 7) * 2;
    const int ty = tid >> 4, tx = tid & 15;
    float acc[4][2] = {};
    for (int kb = z * KC; kb < (z + 1) * KC; kb += BK) {
        float4 av = *(const float4*)(x + (size_t)arow * KX + kb + ak);
        As[ak + 0][arow] = av.x;
        As[ak + 1][arow] = av.y;
        As[ak + 2][arow] = av.z;
        As[ak + 3][arow] = av.w;
        const float* src;
        if (kb < NE + NENC)
            src = Wih + (size_t)(gn + brow) * (NE + NENC) + kb + bk2;
        else
            src = Whh + (size_t)(gn + brow) * ND + (kb - (NE + NENC)) + bk2;
        float2 bv = *(const float2*)src;
        Bs[bk2 + 0][brow] = bv.x;
        Bs[bk2 + 1][brow] = bv.y;
        __syncthreads();
        #pragma unroll
        for (int kk = 0; kk < BK; ++kk) {
            float a[4], bb[2];
            #pragma unroll
            for (int i = 0; i < 4; ++i) a[i] = As[kk][ty * 4 + i];
            bb[0] = Bs[kk][tx * 2 + 0];
            bb[1] = Bs[kk][tx * 2 + 1];
            #pragma unroll
            for (int i = 0; i < 4; ++i) {
                acc[i][0] = fmaf(a[i], bb[0], acc[i][0]);
                acc[i][1] = fmaf(a[i], bb[1], acc[i][1]);
            }
        }
        __syncthreads();
    }
    float* outp = gpart + (size_t)z * NB * (4 * ND);
    #pragma unroll
    for (int i = 0; i < 4; ++i)
        #pragma unroll
        for (int j = 0; j < 2; ++j)
            outp[(size_t)(ty * 4 + i) * (4 * ND) + gn + tx * 2 + j] = acc[i][j];
}

// ---------------------------------------------------------------------------
// K_lstm: sum split-K partials + biases -> i,f,g,o -> update h,c in place.
// ---------------------------------------------------------------------------
__launch_bounds__(256)
__global__ void k_lstm(const float* __restrict__ gpart,  // (4,B,2048)
                       const float* __restrict__ bih,    // (2048)
                       const float* __restrict__ bhh,    // (2048)
                       float* __restrict__ h, float* __restrict__ c)
{
    const int idx = blockIdx.x * 256 + threadIdx.x;  // 0..32767
    const int b = idx >> 9, d = idx & 511;
    constexpr int G = 4 * ND;
    float gi = bih[d]        + bhh[d];
    float gf = bih[d + 512]  + bhh[d + 512];
    float gg = bih[d + 1024] + bhh[d + 1024];
    float go = bih[d + 1536] + bhh[d + 1536];
    #pragma unroll
    for (int z = 0; z < 4; ++z) {
        const float* gp = gpart + ((size_t)z * NB + b) * G;
        gi += gp[d];
        gf += gp[d + 512];
        gg += gp[d + 1024];
        go += gp[d + 1536];
    }
    float i = 1.f / (1.f + expf(-gi));
    float f = 1.f / (1.f + expf(-gf));
    float g = tanhf(gg);
    float o = 1.f / (1.f + expf(-go));
    float cn = f * c[idx] + i * g;
    float hn = o * tanhf(cn);
    c[idx] = cn;
    h[idx] = hn;
}

// ---------------------------------------------------------------------------
// K_logits: (B,V) = h(B,512) @ W_out(512,V) + b_out -> f32 d_out[:, t, :]
// BM=64 (all B), BN=64, BK=16, 4x4 per thread, N-edge guarded (V=10000).
// ---------------------------------------------------------------------------
__launch_bounds__(256)
__global__ void k_logits(int t, const float* __restrict__ h,
                         const float* __restrict__ Wout, // (512, V)
                         const float* __restrict__ bout, // (V)
                         float* __restrict__ out)        // (B,T,V) f32
{
    constexpr int BN = 64, BK = 16;
    __shared__ float As[BK][NB + 1];
    __shared__ float Bs[BK][BN + 1];
    const int tid = threadIdx.x;
    const int gn = blockIdx.x * BN;
    const int arow = tid >> 2, ak = (tid & 3) * 4;
    const int bkr = tid >> 4, bn = (tid & 15) * 4;
    const int ty = tid >> 4, tx = tid & 15;
    float acc[4][4] = {};
    const bool full = (gn + BN <= NV);
    for (int kb = 0; kb < ND; kb += BK) {
        float4 av = *(const float4*)(h + (size_t)arow * ND + kb + ak);
        As[ak + 0][arow] = av.x;
        As[ak + 1][arow] = av.y;
        As[ak + 2][arow] = av.z;
        As[ak + 3][arow] = av.w;
        const float* src = Wout + (size_t)(kb + bkr) * NV + gn + bn;
        if (full) {
            float4 bv = *(const float4*)src;
            Bs[bkr][bn + 0] = bv.x;
            Bs[bkr][bn + 1] = bv.y;
            Bs[bkr][bn + 2] = bv.z;
            Bs[bkr][bn + 3] = bv.w;
        } else {
            #pragma unroll
            for (int i = 0; i < 4; ++i)
                Bs[bkr][bn + i] = (gn + bn + i < NV) ? src[i] : 0.f;
        }
        __syncthreads();
        #pragma unroll
        for (int kk = 0; kk < BK; ++kk) {
            float a[4], bb[4];
            #pragma unroll
            for (int i = 0; i < 4; ++i) a[i] = As[kk][ty * 4 + i];
            #pragma unroll
            for (int j = 0; j < 4; ++j) bb[j] = Bs[kk][tx * 4 + j];
            #pragma unroll
            for (int i = 0; i < 4; ++i)
                #pragma unroll
                for (int j = 0; j < 4; ++j)
                    acc[i][j] = fmaf(a[i], bb[j], acc[i][j]);
        }
        __syncthreads();
    }
    #pragma unroll
    for (int i = 0; i < 4; ++i) {
        const int b = ty * 4 + i;
        #pragma unroll
        for (int j = 0; j < 4; ++j) {
            const int v = gn + tx * 4 + j;
            if (v < NV)
                out[((size_t)b * NT + t) * NV + v] = acc[i][j] + bout[v];
        }
    }
}

// ---------------------------------------------------------------------------
extern "C" void kernel_launch(void* const* d_in, const int* in_sizes, int n_in,
                              void* d_out, int out_size, void* d_ws, size_t ws_size,
                              hipStream_t stream) {
    const float* enc  = (const float*)d_in[0];
    const int*   caps = (const int*)d_in[1];
    const float* embt = (const float*)d_in[2];
    const float* Wea  = (const float*)d_in[3];
    const float* bea  = (const float*)d_in[4];
    const float* Wda  = (const float*)d_in[5];
    const float* bda  = (const float*)d_in[6];
    const float* wf   = (const float*)d_in[7];
    const float* bfs  = (const float*)d_in[8];
    const float* Wih  = (const float*)d_in[9];
    const float* bih  = (const float*)d_in[10];
    const float* Whh  = (const float*)d_in[11];
    const float* bhh  = (const float*)d_in[12];
    const float* Wh0  = (const float*)d_in[13];
    const float* bh0  = (const float*)d_in[14];
    const float* Wc0  = (const float*)d_in[15];
    const float* bc0  = (const float*)d_in[16];
    const float* Wout = (const float*)d_in[17];
    const float* bout = (const float*)d_in[18];

    float* out = (float*)d_out;                       // logits (B,T,V) f32
    float* alpha_out = out + (size_t)NB * NT * NV;    // alphas (B,T,L) f32

    float* ws = (float*)d_ws;
    float* enc_proj = ws;                                   // 64*49*512
    float* h        = enc_proj + (size_t)NB * NL * NA;      // 64*512
    float* c        = h + NB * ND;                          // 64*512
    float* x        = c + NB * ND;                          // 64*3072
    float* gpart    = x + (size_t)NB * KX;                  // 4*64*2048
    float* mean     = gpart + (size_t)4 * NB * 4 * ND;      // 64*2048
    float* dp       = mean + (size_t)NB * NENC;             // 64*512

    hipLaunchKernelGGL(k_mean, dim3(NB, NENC / 256), dim3(256), 0, stream,
                       enc, mean);
    hipLaunchKernelGGL(k_init_gemm, dim3(2 * ND / 64), dim3(256), 0, stream,
                       mean, Wh0, bh0, Wc0, bc0, h, c);
    hipLaunchKernelGGL(k_encproj, dim3(NB * NL / 64, NA / 64), dim3(256), 0, stream,
                       enc, Wea, bea, enc_proj);

    for (int t = 0; t < NT; ++t) {
        hipLaunchKernelGGL(k_decproj, dim3(NA / 64), dim3(256), 0, stream,
                           h, Wda, bda, dp);
        hipLaunchKernelGGL(k_att, dim3(NB), dim3(256), 0, stream,
                           t, h, dp, enc_proj, enc, wf, bfs, embt, caps, x, alpha_out);
        hipLaunchKernelGGL(k_gates, dim3((4 * ND) / 32, 4), dim3(256), 0, stream,
                           x, Wih, Whh, gpart);
        hipLaunchKernelGGL(k_lstm, dim3(NB * ND / 256), dim3(256), 0, stream,
                           gpart, bih, bhh, h, c);
        hipLaunchKernelGGL(k_logits, dim3((NV + 63) / 64), dim3(256), 0, stream,
                           t, h, Wout, bout, out);
    }
}

// Round 5
// 1713.290 us; speedup vs baseline: 2.3085x; 2.1170x over previous
//
#include <hip/hip_runtime.h>
#include <hip/hip_bf16.h>

// Problem dims
constexpr int NV   = 10000;  // vocab
constexpr int NE   = 512;    // embed
constexpr int NENC = 2048;   // encoder dim
constexpr int ND   = 512;    // decoder dim
constexpr int NA   = 512;    // attention dim
constexpr int NB   = 64;     // batch
constexpr int NL   = 49;     // locations
constexpr int NT   = 20;     // steps
constexpr int KX   = NE + NENC + ND;  // 3072 : x = [emb | context | h]
constexpr int KIH  = NE + NENC;       // 2560 : W_ih inner dim

typedef short bfrag __attribute__((ext_vector_type(8)));   // 8 bf16 (4 VGPRs)
typedef float f32x4 __attribute__((ext_vector_type(4)));   // MFMA acc

__device__ __forceinline__ float us2f(unsigned short u) {
    union { unsigned int i; float f; } x; x.i = (unsigned int)u << 16; return x.f;
}
__device__ __forceinline__ unsigned short f2us(float f) {  // RNE f32->bf16
    union { float f_; unsigned int u; } x; x.f_ = f;
    unsigned int r = (x.u + 0x7fffu + ((x.u >> 16) & 1u)) >> 16;
    return (unsigned short)r;
}

// ---------------------------------------------------------------------------
// K_mean: mean over L. grid (B, NENC/256). Coalesced.
// ---------------------------------------------------------------------------
__launch_bounds__(256)
__global__ void k_mean(const float* __restrict__ enc, float* __restrict__ mean)
{
    const int b = blockIdx.x;
    const int e = blockIdx.y * 256 + threadIdx.x;
    const float* p = enc + (size_t)b * NL * NENC + e;
    float s = 0.f;
    #pragma unroll 7
    for (int l = 0; l < NL; ++l) s += p[(size_t)l * NENC];
    mean[(size_t)b * NENC + e] = s * (1.0f / NL);
}

// ---------------------------------------------------------------------------
// K_init_gemm: h(bf16),c(f32) = mean(64,2048) @ [W_init_h|W_init_c] + bias.
// ---------------------------------------------------------------------------
__launch_bounds__(256)
__global__ void k_init_gemm(const float* __restrict__ mean,
                            const float* __restrict__ Wh, const float* __restrict__ bh,
                            const float* __restrict__ Wc, const float* __restrict__ bc,
                            unsigned short* __restrict__ hbf, float* __restrict__ c)
{
    constexpr int BN = 64, BK = 16;
    __shared__ float As[BK][NB + 1];
    __shared__ float Bs[BK][BN + 1];
    const int tid = threadIdx.x;
    const bool isC = blockIdx.x >= (ND / BN);
    const float* W    = isC ? Wc : Wh;
    const float* bias = isC ? bc : bh;
    const int gn = (blockIdx.x - (isC ? ND / BN : 0)) * BN;
    const int arow = tid >> 2, ak = (tid & 3) * 4;
    const int bkr = tid >> 4, bn = (tid & 15) * 4;
    const int ty = tid >> 4, tx = tid & 15;
    float acc[4][4] = {};
    for (int kb = 0; kb < NENC; kb += BK) {
        float4 av = *(const float4*)(mean + (size_t)arow * NENC + kb + ak);
        As[ak + 0][arow] = av.x; As[ak + 1][arow] = av.y;
        As[ak + 2][arow] = av.z; As[ak + 3][arow] = av.w;
        float4 bv = *(const float4*)(W + (size_t)(kb + bkr) * ND + gn + bn);
        Bs[bkr][bn + 0] = bv.x; Bs[bkr][bn + 1] = bv.y;
        Bs[bkr][bn + 2] = bv.z; Bs[bkr][bn + 3] = bv.w;
        __syncthreads();
        #pragma unroll
        for (int kk = 0; kk < BK; ++kk) {
            float a[4], bb[4];
            #pragma unroll
            for (int i = 0; i < 4; ++i) a[i] = As[kk][ty * 4 + i];
            #pragma unroll
            for (int j = 0; j < 4; ++j) bb[j] = Bs[kk][tx * 4 + j];
            #pragma unroll
            for (int i = 0; i < 4; ++i)
                #pragma unroll
                for (int j = 0; j < 4; ++j)
                    acc[i][j] = fmaf(a[i], bb[j], acc[i][j]);
        }
        __syncthreads();
    }
    #pragma unroll
    for (int i = 0; i < 4; ++i)
        #pragma unroll
        for (int j = 0; j < 4; ++j) {
            int n = gn + tx * 4 + j;
            float v = acc[i][j] + bias[n];
            if (isC) c[(size_t)(ty * 4 + i) * ND + n] = v;
            else     hbf[(size_t)(ty * 4 + i) * ND + n] = f2us(v);
        }
}

// ---------------------------------------------------------------------------
// K_cvt: f32 -> bf16 flat copy (n multiple of 4).
// ---------------------------------------------------------------------------
__launch_bounds__(256)
__global__ void k_cvt(const float* __restrict__ src, unsigned short* __restrict__ dst, int n)
{
    int i = (blockIdx.x * 256 + threadIdx.x) * 4;
    if (i < n) {
        float4 v = *(const float4*)(src + i);
        dst[i + 0] = f2us(v.x); dst[i + 1] = f2us(v.y);
        dst[i + 2] = f2us(v.z); dst[i + 3] = f2us(v.w);
    }
}

// ---------------------------------------------------------------------------
// K_transpose: (K,N) f32 -> (N,K) bf16.  grid (ceil(N/32), K/32), 256 thr.
// ---------------------------------------------------------------------------
__launch_bounds__(256)
__global__ void k_transpose(const float* __restrict__ src, unsigned short* __restrict__ dst,
                            int K, int N)
{
    __shared__ float t[32][33];
    const int nb = blockIdx.x * 32, kb = blockIdx.y * 32;
    const int tx = threadIdx.x & 31, ty = threadIdx.x >> 5;  // ty 0..7
    #pragma unroll
    for (int i = ty; i < 32; i += 8) {
        int n = nb + tx;
        t[i][tx] = (n < N) ? src[(size_t)(kb + i) * N + n] : 0.f;
    }
    __syncthreads();
    #pragma unroll
    for (int i = ty; i < 32; i += 8) {
        int n = nb + i;
        if (n < N) dst[(size_t)n * K + kb + tx] = f2us(t[tx][i]);
    }
}

// ---------------------------------------------------------------------------
// K_encproj_mfma: epb(3136,512)bf16 = encb(3136,2048) @ WeaT(512,2048)^T + bias
// wave = one 16x16 tile; block = 4 m-tiles of one n-tile. grid 49*32=1568.
// ---------------------------------------------------------------------------
__launch_bounds__(256)
__global__ void k_encproj_mfma(const unsigned short* __restrict__ encb,
                               const unsigned short* __restrict__ WeaT,
                               const float* __restrict__ bias,
                               unsigned short* __restrict__ epb)
{
    const int wave = threadIdx.x >> 6, lane = threadIdx.x & 63;
    const int ntile = blockIdx.x & 31;
    const int mg    = blockIdx.x >> 5;             // 0..48
    const int m0 = (mg * 4 + wave) * 16;
    const int n0 = ntile * 16;
    const int r = lane & 15, quad = lane >> 4;
    const unsigned short* ap = encb + (size_t)(m0 + r) * NENC + quad * 8;
    const unsigned short* bp = WeaT + (size_t)(n0 + r) * NENC + quad * 8;
    f32x4 acc = {0.f, 0.f, 0.f, 0.f};
    #pragma unroll 8
    for (int k = 0; k < NENC; k += 32) {
        bfrag a = *(const bfrag*)(ap + k);
        bfrag b = *(const bfrag*)(bp + k);
        acc = __builtin_amdgcn_mfma_f32_16x16x32_bf16(a, b, acc, 0, 0, 0);
    }
    const float bv = bias[n0 + r];
    #pragma unroll
    for (int i = 0; i < 4; ++i) {
        int m = m0 + quad * 4 + i;
        epb[(size_t)m * NA + n0 + r] = f2us(acc[i] + bv);
    }
}

// ---------------------------------------------------------------------------
// K_decproj_mfma: dp(64,512)f32 = hbf(64,512) @ WdaT(512,512)^T + bda. grid 32.
// ---------------------------------------------------------------------------
__launch_bounds__(256)
__global__ void k_decproj_mfma(const unsigned short* __restrict__ hbf,
                               const unsigned short* __restrict__ WdaT,
                               const float* __restrict__ bda,
                               float* __restrict__ dp)
{
    const int wave = threadIdx.x >> 6, lane = threadIdx.x & 63;
    const int m0 = wave * 16, n0 = blockIdx.x * 16;
    const int r = lane & 15, quad = lane >> 4;
    const unsigned short* ap = hbf + (size_t)(m0 + r) * ND + quad * 8;
    const unsigned short* bp = WdaT + (size_t)(n0 + r) * ND + quad * 8;
    f32x4 acc = {0.f, 0.f, 0.f, 0.f};
    #pragma unroll
    for (int k = 0; k < ND; k += 32) {
        bfrag a = *(const bfrag*)(ap + k);
        bfrag b = *(const bfrag*)(bp + k);
        acc = __builtin_amdgcn_mfma_f32_16x16x32_bf16(a, b, acc, 0, 0, 0);
    }
    const float bv = bda[n0 + r];
    #pragma unroll
    for (int i = 0; i < 4; ++i) {
        int m = m0 + quad * 4 + i;
        dp[(size_t)m * NA + n0 + r] = acc[i] + bv;
    }
}

// ---------------------------------------------------------------------------
// K_att: one block per b. scores=relu(ep+dp)@wf+b -> softmax -> alpha (f32 out)
// context from encb (bf16) -> x (bf16). Also x=[emb|context|h].
// ---------------------------------------------------------------------------
__launch_bounds__(256)
__global__ void k_att(int t,
                      const unsigned short* __restrict__ hbf,   // (B,D) bf16
                      const float* __restrict__ dpg,            // (B,A) f32
                      const unsigned short* __restrict__ epb,   // (B,L,A) bf16
                      const unsigned short* __restrict__ encb,  // (B,L,ENC) bf16
                      const float* __restrict__ wf,             // (A)
                      const float* __restrict__ bfs,            // scalar
                      const float* __restrict__ embt,           // (V,E) f32
                      const int* __restrict__ captions,         // (B,T)
                      unsigned short* __restrict__ x,           // (B,KX) bf16
                      float* __restrict__ alpha_out)            // (B,T,L) f32
{
    __shared__ float dp[NA];
    __shared__ float al[64];
    const int b = blockIdx.x, tid = threadIdx.x;

    for (int d = tid; d < ND; d += 256)
        x[(size_t)b * KX + NE + NENC + d] = hbf[(size_t)b * ND + d];  // h tail
    for (int a = tid; a < NA; a += 256)
        dp[a] = dpg[(size_t)b * NA + a];
    const int tok = captions[b * NT + t];
    for (int j = tid; j < NE; j += 256)
        x[(size_t)b * KX + j] = f2us(embt[(size_t)tok * NE + j]);
    __syncthreads();

    // scores: one wave per l
    const int wave = tid >> 6, lane = tid & 63;
    const float bfull = bfs[0];
    for (int l = wave; l < NL; l += 4) {
        const unsigned short* ep = epb + ((size_t)b * NL + l) * NA;
        float s = 0.f;
        #pragma unroll
        for (int a = lane; a < NA; a += 64) {
            float v = us2f(ep[a]) + dp[a];
            v = v > 0.f ? v : 0.f;
            s = fmaf(v, wf[a], s);
        }
        #pragma unroll
        for (int off = 32; off > 0; off >>= 1) s += __shfl_down(s, off, 64);
        if (lane == 0) al[l] = s + bfull;
    }
    __syncthreads();

    // softmax over L=49 (first wave)
    if (tid < 64) {
        float v = (tid < NL) ? al[tid] : -1e30f;
        float m = v;
        #pragma unroll
        for (int off = 32; off > 0; off >>= 1) m = fmaxf(m, __shfl_xor(m, off, 64));
        float e = (tid < NL) ? expf(v - m) : 0.f;
        float s = e;
        #pragma unroll
        for (int off = 32; off > 0; off >>= 1) s += __shfl_xor(s, off, 64);
        float a = e / s;
        if (tid < NL) {
            al[tid] = a;
            alpha_out[((size_t)b * NT + t) * NL + tid] = a;
        }
    }
    __syncthreads();

    // context -> x middle, bf16. thread covers 4 consecutive e, two passes.
    #pragma unroll
    for (int part = 0; part < 2; ++part) {
        const int e = part * 1024 + tid * 4;
        const unsigned short* p = encb + (size_t)b * NL * NENC + e;
        float s0 = 0.f, s1 = 0.f, s2 = 0.f, s3 = 0.f;
        #pragma unroll 7
        for (int l = 0; l < NL; ++l) {
            ushort4 v = *(const ushort4*)(p + (size_t)l * NENC);
            float a = al[l];
            s0 = fmaf(a, us2f(v.x), s0);
            s1 = fmaf(a, us2f(v.y), s1);
            s2 = fmaf(a, us2f(v.z), s2);
            s3 = fmaf(a, us2f(v.w), s3);
        }
        unsigned short* xo = x + (size_t)b * KX + NE + e;
        xo[0] = f2us(s0); xo[1] = f2us(s1); xo[2] = f2us(s2); xo[3] = f2us(s3);
    }
}

// ---------------------------------------------------------------------------
// K_gates_mfma: gates(64,2048)f32 = x(64,3072) @ [Wihb|Whhb]^T. grid 128.
// ---------------------------------------------------------------------------
__launch_bounds__(256)
__global__ void k_gates_mfma(const unsigned short* __restrict__ x,     // (64,3072)
                             const unsigned short* __restrict__ Wihb,  // (2048,2560)
                             const unsigned short* __restrict__ Whhb,  // (2048,512)
                             float* __restrict__ gates)                // (64,2048)
{
    const int wave = threadIdx.x >> 6, lane = threadIdx.x & 63;
    const int m0 = wave * 16, n0 = blockIdx.x * 16;
    const int r = lane & 15, quad = lane >> 4;
    const unsigned short* ap  = x + (size_t)(m0 + r) * KX + quad * 8;
    const unsigned short* bp1 = Wihb + (size_t)(n0 + r) * KIH + quad * 8;
    const unsigned short* bp2 = Whhb + (size_t)(n0 + r) * ND + quad * 8;
    f32x4 acc = {0.f, 0.f, 0.f, 0.f};
    #pragma unroll 8
    for (int k = 0; k < KIH; k += 32) {
        bfrag a = *(const bfrag*)(ap + k);
        bfrag b = *(const bfrag*)(bp1 + k);
        acc = __builtin_amdgcn_mfma_f32_16x16x32_bf16(a, b, acc, 0, 0, 0);
    }
    #pragma unroll
    for (int k = 0; k < ND; k += 32) {
        bfrag a = *(const bfrag*)(ap + KIH + k);
        bfrag b = *(const bfrag*)(bp2 + k);
        acc = __builtin_amdgcn_mfma_f32_16x16x32_bf16(a, b, acc, 0, 0, 0);
    }
    #pragma unroll
    for (int i = 0; i < 4; ++i) {
        int m = m0 + quad * 4 + i;
        gates[(size_t)m * (4 * ND) + n0 + r] = acc[i];
    }
}

// ---------------------------------------------------------------------------
// K_lstm: gates + biases -> i,f,g,o -> c (f32), h (bf16). grid 128.
// ---------------------------------------------------------------------------
__launch_bounds__(256)
__global__ void k_lstm(const float* __restrict__ gates,  // (B,2048)
                       const float* __restrict__ bih, const float* __restrict__ bhh,
                       unsigned short* __restrict__ hbf, float* __restrict__ c)
{
    const int idx = blockIdx.x * 256 + threadIdx.x;  // 0..32767
    const int b = idx >> 9, d = idx & 511;
    const float* gp = gates + (size_t)b * (4 * ND);
    float gi = gp[d]        + bih[d]        + bhh[d];
    float gf = gp[d + 512]  + bih[d + 512]  + bhh[d + 512];
    float gg = gp[d + 1024] + bih[d + 1024] + bhh[d + 1024];
    float go = gp[d + 1536] + bih[d + 1536] + bhh[d + 1536];
    float i = 1.f / (1.f + expf(-gi));
    float f = 1.f / (1.f + expf(-gf));
    float g = tanhf(gg);
    float o = 1.f / (1.f + expf(-go));
    float cn = f * c[idx] + i * g;
    float hn = o * tanhf(cn);
    c[idx] = cn;
    hbf[idx] = f2us(hn);
}

// ---------------------------------------------------------------------------
// K_logits_mfma: out[:,t,:](64,10000) = hbf @ WoutT(10000,512)^T + bout. grid 625.
// ---------------------------------------------------------------------------
__launch_bounds__(256)
__global__ void k_logits_mfma(int t,
                              const unsigned short* __restrict__ hbf,    // (64,512)
                              const unsigned short* __restrict__ WoutT,  // (10000,512)
                              const float* __restrict__ bout,            // (10000)
                              float* __restrict__ out)                   // (B,T,V)
{
    const int wave = threadIdx.x >> 6, lane = threadIdx.x & 63;
    const int m0 = wave * 16, n0 = blockIdx.x * 16;   // 625*16 = 10000 exact
    const int r = lane & 15, quad = lane >> 4;
    const unsigned short* ap = hbf + (size_t)(m0 + r) * ND + quad * 8;
    const unsigned short* bp = WoutT + (size_t)(n0 + r) * ND + quad * 8;
    f32x4 acc = {0.f, 0.f, 0.f, 0.f};
    #pragma unroll
    for (int k = 0; k < ND; k += 32) {
        bfrag a = *(const bfrag*)(ap + k);
        bfrag b = *(const bfrag*)(bp + k);
        acc = __builtin_amdgcn_mfma_f32_16x16x32_bf16(a, b, acc, 0, 0, 0);
    }
    const float bv = bout[n0 + r];
    #pragma unroll
    for (int i = 0; i < 4; ++i) {
        int m = m0 + quad * 4 + i;
        out[((size_t)m * NT + t) * NV + n0 + r] = acc[i] + bv;
    }
}

// ---------------------------------------------------------------------------
extern "C" void kernel_launch(void* const* d_in, const int* in_sizes, int n_in,
                              void* d_out, int out_size, void* d_ws, size_t ws_size,
                              hipStream_t stream) {
    const float* enc  = (const float*)d_in[0];
    const int*   caps = (const int*)d_in[1];
    const float* embt = (const float*)d_in[2];
    const float* Wea  = (const float*)d_in[3];
    const float* bea  = (const float*)d_in[4];
    const float* Wda  = (const float*)d_in[5];
    const float* bda  = (const float*)d_in[6];
    const float* wf   = (const float*)d_in[7];
    const float* bfs  = (const float*)d_in[8];
    const float* Wih  = (const float*)d_in[9];
    const float* bih  = (const float*)d_in[10];
    const float* Whh  = (const float*)d_in[11];
    const float* bhh  = (const float*)d_in[12];
    const float* Wh0  = (const float*)d_in[13];
    const float* bh0  = (const float*)d_in[14];
    const float* Wc0  = (const float*)d_in[15];
    const float* bc0  = (const float*)d_in[16];
    const float* Wout = (const float*)d_in[17];
    const float* bout = (const float*)d_in[18];

    float* out = (float*)d_out;                       // logits (B,T,V) f32
    float* alpha_out = out + (size_t)NB * NT * NV;    // alphas (B,T,L) f32

    // ---- workspace carve-up (16B aligned throughout) ----
    char* w = (char*)d_ws;
    float* mean  = (float*)w;                 w += (size_t)NB * NENC * 4;        // 512 KB
    float* c     = (float*)w;                 w += (size_t)NB * ND * 4;          // 128 KB
    float* dp    = (float*)w;                 w += (size_t)NB * NA * 4;          // 128 KB
    float* gates = (float*)w;                 w += (size_t)NB * 4 * ND * 4;      // 512 KB
    unsigned short* hbf   = (unsigned short*)w; w += (size_t)NB * ND * 2;        // 64 KB
    unsigned short* x     = (unsigned short*)w; w += (size_t)NB * KX * 2;        // 384 KB
    unsigned short* epb   = (unsigned short*)w; w += (size_t)NB * NL * NA * 2;   // 3.2 MB
    unsigned short* encb  = (unsigned short*)w; w += (size_t)NB * NL * NENC * 2; // 12.8 MB
    unsigned short* Wihb  = (unsigned short*)w; w += (size_t)4 * ND * KIH * 2;   // 10.5 MB
    unsigned short* Whhb  = (unsigned short*)w; w += (size_t)4 * ND * ND * 2;    // 2 MB
    unsigned short* WeaT  = (unsigned short*)w; w += (size_t)NA * NENC * 2;      // 2 MB
    unsigned short* WdaT  = (unsigned short*)w; w += (size_t)NA * ND * 2;        // 0.5 MB
    unsigned short* WoutT = (unsigned short*)w; w += (size_t)NV * ND * 2;        // 10.2 MB

    // ---- one-time setup ----
    hipLaunchKernelGGL(k_mean, dim3(NB, NENC / 256), dim3(256), 0, stream, enc, mean);
    hipLaunchKernelGGL(k_init_gemm, dim3(2 * ND / 64), dim3(256), 0, stream,
                       mean, Wh0, bh0, Wc0, bc0, hbf, c);
    {
        int n = NB * NL * NENC;
        hipLaunchKernelGGL(k_cvt, dim3(n / 4 / 256), dim3(256), 0, stream, enc, encb, n);
    }
    {
        int n = 4 * ND * KIH;
        hipLaunchKernelGGL(k_cvt, dim3(n / 4 / 256), dim3(256), 0, stream, Wih, Wihb, n);
    }
    {
        int n = 4 * ND * ND;
        hipLaunchKernelGGL(k_cvt, dim3(n / 4 / 256), dim3(256), 0, stream, Whh, Whhb, n);
    }
    hipLaunchKernelGGL(k_transpose, dim3(NA / 32, NENC / 32), dim3(256), 0, stream,
                       Wea, WeaT, NENC, NA);
    hipLaunchKernelGGL(k_transpose, dim3(NA / 32, ND / 32), dim3(256), 0, stream,
                       Wda, WdaT, ND, NA);
    hipLaunchKernelGGL(k_transpose, dim3((NV + 31) / 32, ND / 32), dim3(256), 0, stream,
                       Wout, WoutT, ND, NV);
    hipLaunchKernelGGL(k_encproj_mfma, dim3((NB * NL / 64) * (NA / 16)), dim3(256), 0, stream,
                       encb, WeaT, bea, epb);

    // ---- 20 sequential decoder steps ----
    for (int t = 0; t < NT; ++t) {
        hipLaunchKernelGGL(k_decproj_mfma, dim3(NA / 16), dim3(256), 0, stream,
                           hbf, WdaT, bda, dp);
        hipLaunchKernelGGL(k_att, dim3(NB), dim3(256), 0, stream,
                           t, hbf, dp, epb, encb, wf, bfs, embt, caps, x, alpha_out);
        hipLaunchKernelGGL(k_gates_mfma, dim3(4 * ND / 16), dim3(256), 0, stream,
                           x, Wihb, Whhb, gates);
        hipLaunchKernelGGL(k_lstm, dim3(NB * ND / 256), dim3(256), 0, stream,
                           gates, bih, bhh, hbf, c);
        hipLaunchKernelGGL(k_logits_mfma, dim3(NV / 16), dim3(256), 0, stream,
                           t, hbf, WoutT, bout, out);
    }
}